// Round 11
// baseline (361.487 us; speedup 1.0000x reference)
//
#include <hip/hip_runtime.h>
#include <hip/hip_bf16.h>

// ---------------------------------------------------------------------------
// PolygonPredictionLayer: B=8,P=64,N=512,T=196(->224),S=100(->112),C=256,H=8,dh=32
// R11: kvproj v8 -- t-half blocks (grid 512x2, LDS 59KB -> 2 blocks/CU),
//   weights streamed from L2 (128-reg cap, no spill), pk2+b64 packed staging,
//   pad region (t>=196) never computed/written. attn_fuse v2 + in-register
//   V-pad zeroing on the last chunk (K-pad already masked pre-exp).
// ---------------------------------------------------------------------------

typedef __attribute__((ext_vector_type(8))) short bf16x8;
typedef __attribute__((ext_vector_type(4))) float f32x4;

__device__ __forceinline__ float bf2f(ushort u) {
    union { float f; uint u32; } v; v.u32 = ((uint)u) << 16; return v.f;
}
__device__ __forceinline__ ushort f2bf(float f) {
    union { float f; uint u; } v; v.f = f;
    uint r = v.u + 0x7FFF + ((v.u >> 16) & 1);
    return (ushort)(r >> 16);
}
__device__ __forceinline__ uint pk2(float a, float b) {
    __hip_bfloat162 h = __float22bfloat162_rn(make_float2(a, b));
    union { __hip_bfloat162 h2; uint u; } c; c.h2 = h; return c.u;
}
__device__ __forceinline__ f32x4 MFMA(bf16x8 a, bf16x8 b, f32x4 c) {
    return __builtin_amdgcn_mfma_f32_16x16x32_bf16(a, b, c, 0, 0, 0);
}

#define SCALE_DH 0.17677669529663687f  // 1/sqrt(32)

// ---------------- prep: weights+biases -> ws tables, qcp zero ---------------
#define TOTALW (2337 * 256)
#define QCPN   (8 * 8 * 112 * 32)
#define NBIAS  2337

__global__ void prep_kernel(const float* w0, const float* w1_, const float* w2_,
                            const float* w3, const float* w4, const float* w5,
                            const float* w6, const float* w7, const float* w8,
                            const float* w9, const float* w10,
                            const float* b0, const float* b1_, const float* b2_,
                            const float* b3, const float* b4, const float* b5,
                            const float* b6, const float* b7, const float* b8,
                            const float* b9, const float* b10,
                            ushort* wbf, float* bias, ushort* qcp)
{
    for (size_t i = blockIdx.x * blockDim.x + threadIdx.x;
         i < (size_t)TOTALW + QCPN + NBIAS; i += (size_t)gridDim.x * blockDim.x) {
        if (i < TOTALW) {
            int row = (int)(i >> 8), col = (int)(i & 255);
            const float* sp; int base;
            if      (row < 256)  { sp = w0;  base = 0; }
            else if (row < 512)  { sp = w1_; base = 256; }
            else if (row < 768)  { sp = w2_; base = 512; }
            else if (row < 1024) { sp = w3;  base = 768; }
            else if (row < 1280) { sp = w4;  base = 1024; }
            else if (row < 1536) { sp = w5;  base = 1280; }
            else if (row < 1792) { sp = w6;  base = 1536; }
            else if (row < 2048) { sp = w7;  base = 1792; }
            else if (row < 2304) { sp = w8;  base = 2048; }
            else if (row < 2336) { sp = w9;  base = 2304; }
            else                 { sp = w10; base = 2336; }
            wbf[i] = f2bf(sp[(size_t)(row - base) * 256 + col]);
        } else if (i < (size_t)TOTALW + QCPN) {
            qcp[i - TOTALW] = 0;
        } else {
            int idx = (int)(i - TOTALW - QCPN);
            const float* sp; int base;
            if      (idx < 256)  { sp = b0;  base = 0; }
            else if (idx < 512)  { sp = b1_; base = 256; }
            else if (idx < 768)  { sp = b2_; base = 512; }
            else if (idx < 1024) { sp = b3;  base = 768; }
            else if (idx < 1280) { sp = b4;  base = 1024; }
            else if (idx < 1536) { sp = b5;  base = 1280; }
            else if (idx < 1792) { sp = b6;  base = 1536; }
            else if (idx < 2048) { sp = b7;  base = 1792; }
            else if (idx < 2304) { sp = b8;  base = 2048; }
            else if (idx < 2336) { sp = b9;  base = 2304; }
            else                 { sp = b10; base = 2336; }
            bias[idx] = sp[idx - base];
        }
    }
}

// ---------------- generic small GEMM: out = A @ W^T + bias -----------------
template<int ASRC, int GS, int EPI>
__global__ __launch_bounds__(256)
void gemm_rows(const void* Aptr, const ushort* Wall, const float* Ball,
               ushort* Out, int M, int Wrow0, int Brow0, int ldo)
{
    __shared__ ushort As[64 * 40];
    __shared__ ushort Bs[128 * 40];
    int tid = threadIdx.x;
    int lane = tid & 63, w = tid >> 6;
    int lr = lane & 15, lg = lane >> 4;
    int r0 = blockIdx.x * 64;
    int j0 = blockIdx.y * 128;

    f32x4 acc[4][2];
    #pragma unroll
    for (int mt = 0; mt < 4; ++mt)
        #pragma unroll
        for (int nt = 0; nt < 2; ++nt) { f32x4 z = {0.f,0.f,0.f,0.f}; acc[mt][nt] = z; }

    for (int ks = 0; ks < 8; ++ks) {
        int c0 = ks * 32;
        {
            int i = tid >> 2, q = tid & 3;
            int r = r0 + i;
            if (ASRC == 0) {
                uint4 v = make_uint4(0u,0u,0u,0u);
                if (r < M) v = *(const uint4*)((const ushort*)Aptr + (size_t)r * 256 + c0 + q * 8);
                *(uint4*)(&As[i * 40 + q * 8]) = v;
            } else {
                uint u[4] = {0u,0u,0u,0u};
                if (r < M) {
                    int g = r / GS, o = r - g * GS;
                    const float* src = (const float*)Aptr + (size_t)g * 256 * GS + o;
                    #pragma unroll
                    for (int k2 = 0; k2 < 4; ++k2) {
                        ushort a0 = f2bf(src[(size_t)(c0 + q * 8 + 2 * k2)     * GS]);
                        ushort a1 = f2bf(src[(size_t)(c0 + q * 8 + 2 * k2 + 1) * GS]);
                        u[k2] = (uint)a0 | ((uint)a1 << 16);
                    }
                }
                *(uint4*)(&As[i * 40 + q * 8]) = make_uint4(u[0], u[1], u[2], u[3]);
            }
        }
        {
            int jj = tid >> 1, half = tid & 1;
            const ushort* src = Wall + (size_t)(Wrow0 + j0 + jj) * 256 + c0 + half * 16;
            ushort* dst = &Bs[jj * 40 + half * 16];
            *(uint4*)(dst)     = *(const uint4*)(src);
            *(uint4*)(dst + 8) = *(const uint4*)(src + 8);
        }
        __syncthreads();
        bf16x8 bfr[2];
        #pragma unroll
        for (int nt = 0; nt < 2; ++nt)
            bfr[nt] = *(const bf16x8*)(&Bs[(w * 32 + nt * 16 + lr) * 40 + lg * 8]);
        #pragma unroll
        for (int mt = 0; mt < 4; ++mt) {
            bf16x8 afr = *(const bf16x8*)(&As[(mt * 16 + lr) * 40 + lg * 8]);
            acc[mt][0] = MFMA(afr, bfr[0], acc[mt][0]);
            acc[mt][1] = MFMA(afr, bfr[1], acc[mt][1]);
        }
        __syncthreads();
    }
    #pragma unroll
    for (int mt = 0; mt < 4; ++mt) {
        #pragma unroll
        for (int nt = 0; nt < 2; ++nt) {
            int jc = j0 + w * 32 + nt * 16 + lr;
            float bias = Ball[Brow0 + jc];
            #pragma unroll
            for (int rg = 0; rg < 4; ++rg) {
                int r = r0 + mt * 16 + lg * 4 + rg;
                if (r >= M) continue;
                float vv = acc[mt][nt][rg] + bias;
                if (EPI == 0) {
                    Out[(size_t)r * ldo + jc] = f2bf(vv);
                } else {
                    int b = r / 100, s = r - b * 100;
                    int h = jc >> 5, d = jc & 31;
                    Out[(((size_t)(b * 8 + h)) * 112 + s) * 32 + d] = f2bf(vv * SCALE_DH);
                }
            }
        }
    }
}

// ---------------- self-attention (tiny, VALU) ------------------------------
__global__ __launch_bounds__(128)
void self_attn(const ushort* qkv, ushort* sav)
{
    __shared__ float kls[100][33];
    __shared__ float vls[100][33];
    __shared__ float sls[100][101];
    int bh = blockIdx.x; int b = bh >> 3, h = bh & 7;
    int tid = threadIdx.x;
    for (int idx = tid; idx < 100 * 32; idx += 128) {
        int t = idx >> 5, d = idx & 31;
        kls[t][d] = bf2f(qkv[((size_t)(b * 100 + t)) * 768 + 256 + h * 32 + d]);
        vls[t][d] = bf2f(qkv[((size_t)(b * 100 + t)) * 768 + 512 + h * 32 + d]);
    }
    __syncthreads();
    if (tid < 100) {
        int s = tid;
        float q[32];
        #pragma unroll
        for (int d = 0; d < 32; ++d)
            q[d] = bf2f(qkv[((size_t)(b * 100 + s)) * 768 + h * 32 + d]) * SCALE_DH;
        float mx = -1e30f;
        for (int t = 0; t < 100; ++t) {
            float sc = 0.f;
            #pragma unroll
            for (int d = 0; d < 32; ++d) sc += q[d] * kls[t][d];
            sls[s][t] = sc; mx = fmaxf(mx, sc);
        }
        float sum = 0.f;
        for (int t = 0; t < 100; ++t) {
            float p = __expf(sls[s][t] - mx);
            sls[s][t] = p; sum += p;
        }
        float inv = 1.f / sum;
        float acc2[32];
        #pragma unroll
        for (int d = 0; d < 32; ++d) acc2[d] = 0.f;
        for (int t = 0; t < 100; ++t) {
            float pv = sls[s][t];
            #pragma unroll
            for (int d = 0; d < 32; ++d) acc2[d] += pv * vls[t][d];
        }
        #pragma unroll
        for (int d = 0; d < 32; ++d)
            sav[((size_t)(b * 100 + s)) * 256 + h * 32 + d] = f2bf(acc2[d] * inv);
    }
}

// ---------------- kvproj v8: kc[n][224][256] t-major, vc[n][256][224] ------
// grid (cnt, 2 th = t-halves), block 512 (8 waves), LDS featT[112][264] bf16
// (59136 B -> 2 blocks/CU). Weights streamed from L2 per (tt,ks) so the wave
// fits the 128-reg cap (launch_bounds(512,4)). Staging: 4 c-rows x 4 t per
// item, pk2 + uint2 writes. Pad t>=196 never computed/written.
__global__ __launch_bounds__(512, 4)
void kvproj(const float* features, const ushort* Wall, const float* Ball,
            ushort* kc, ushort* vc, int n_base)
{
    __shared__ ushort featT[112 * 264];
    int tid = threadIdx.x;
    int lane = tid & 63, w = tid >> 6;
    int lr = lane & 15, lg = lane >> 4;
    int nl = blockIdx.x;
    int n  = n_base + nl;
    int th = blockIdx.y;
    int t0b = th * 112;
    const float* fb = features + (size_t)n * 256 * 196;

    float biask0 = Ball[1280 + w * 32 + lr];
    float biask1 = Ball[1296 + w * 32 + lr];
    float biasv0 = Ball[1536 + w * 32 + lr];
    float biasv1 = Ball[1552 + w * 32 + lr];

    // stage featT[tl][c] = fb[c][t0b+tl]; items = (cg 0..63) x (tgl 0..27)
    #pragma unroll
    for (int it = 0; it < 4; ++it) {
        int idx = tid + it * 512;
        if (idx < 1792) {
            int cg = idx / 28, tgl = idx - cg * 28;
            int t = t0b + tgl * 4;
            float4 z4 = {0.f, 0.f, 0.f, 0.f};
            float4 v0 = z4, v1 = z4, v2 = z4, v3 = z4;
            if (t < 196) {   // t<=192 here, +3 <= 195: never straddles row end
                const float* p = fb + (size_t)(cg * 4) * 196 + t;
                v0 = *(const float4*)(p);
                v1 = *(const float4*)(p + 196);
                v2 = *(const float4*)(p + 392);
                v3 = *(const float4*)(p + 588);
            }
            #pragma unroll
            for (int j = 0; j < 4; ++j) {
                float e0 = (j == 0) ? v0.x : (j == 1) ? v0.y : (j == 2) ? v0.z : v0.w;
                float e1 = (j == 0) ? v1.x : (j == 1) ? v1.y : (j == 2) ? v1.z : v1.w;
                float e2 = (j == 0) ? v2.x : (j == 1) ? v2.y : (j == 2) ? v2.z : v2.w;
                float e3 = (j == 0) ? v3.x : (j == 1) ? v3.y : (j == 2) ? v3.z : v3.w;
                uint2 pr;
                pr.x = pk2(e0, e1);
                pr.y = pk2(e2, e3);
                *(uint2*)(&featT[(tgl * 4 + j) * 264 + cg * 4]) = pr;
            }
        }
    }
    __syncthreads();

    int ttmax = th ? 6 : 7;   // th=1 tile 6 (t 208..223) is all pad: skip
    for (int tt = 0; tt < ttmax; ++tt) {
        f32x4 acc[4];
        #pragma unroll
        for (int m = 0; m < 4; ++m) { f32x4 z = {0.f,0.f,0.f,0.f}; acc[m] = z; }
        #pragma unroll
        for (int ks = 0; ks < 8; ++ks) {
            bf16x8 afr = *(const bf16x8*)(&featT[(tt * 16 + lr) * 264 + ks * 32 + lg * 8]);
            bf16x8 w0 = *(const bf16x8*)(Wall + (size_t)(1280 + w * 32 + lr) * 256 + ks * 32 + lg * 8);
            bf16x8 w1 = *(const bf16x8*)(Wall + (size_t)(1296 + w * 32 + lr) * 256 + ks * 32 + lg * 8);
            bf16x8 w2 = *(const bf16x8*)(Wall + (size_t)(1536 + w * 32 + lr) * 256 + ks * 32 + lg * 8);
            bf16x8 w3 = *(const bf16x8*)(Wall + (size_t)(1552 + w * 32 + lr) * 256 + ks * 32 + lg * 8);
            acc[0] = MFMA(afr, w0, acc[0]);
            acc[1] = MFMA(afr, w1, acc[1]);
            acc[2] = MFMA(afr, w2, acc[2]);
            acc[3] = MFMA(afr, w3, acc[3]);
        }
        // D[row = t-local = lg*4+rg][col = cout-local = lr]
        int t_lo = t0b + tt * 16 + lg * 4;
        if (t_lo < 196) {    // th=1,tt=5: only lg==0 rows (192..195) are real
            size_t kb = ((size_t)nl * 224 + t_lo) * 256 + w * 32 + lr;
            #pragma unroll
            for (int rg = 0; rg < 4; ++rg) {
                kc[kb + (size_t)rg * 256]      = f2bf(acc[0][rg] + biask0);
                kc[kb + (size_t)rg * 256 + 16] = f2bf(acc[1][rg] + biask1);
            }
            ushort4 o2, o3;
            o2.x = f2bf(acc[2][0] + biasv0); o2.y = f2bf(acc[2][1] + biasv0);
            o2.z = f2bf(acc[2][2] + biasv0); o2.w = f2bf(acc[2][3] + biasv0);
            o3.x = f2bf(acc[3][0] + biasv1); o3.y = f2bf(acc[3][1] + biasv1);
            o3.z = f2bf(acc[3][2] + biasv1); o3.w = f2bf(acc[3][3] + biasv1);
            *(ushort4*)(vc + ((size_t)nl * 256 + w * 32 + lr) * 224 + t_lo)      = o2;
            *(ushort4*)(vc + ((size_t)nl * 256 + w * 32 + 16 + lr) * 224 + t_lo) = o3;
        }
    }
}

// ---------------- attn_fuse v2: barrier-free main loop ---------------------
// block 512 (8 waves, wave = head). K/V fragments loaded DIRECTLY from global
// (kc t-major, vc c-major are frag-contiguous); double-buffered in registers.
// Pad handling: K garbage masked pre-exp; V pad elements zeroed in-register
// on the last chunk's prefetch (P=0 x V=0, never 0 x NaN).
// LDS: Pp[8][16][40] @71680 (main loop). Epilogue overlay: OL[112][264] @0 |
// hbar @59392 | scb @60416 | O2[112][264] @71680.
__global__ __launch_bounds__(512, 2)
void attn_fuse(const ushort* qcp, const ushort* kc, const ushort* vc,
               const ushort* Wall, const float* Ball, float* outp, int n_base)
{
    __shared__ char smem[130816];
    ushort* OL  = (ushort*)smem;
    float* hbar = (float*)(smem + 59392);
    float* scb  = (float*)(smem + 60416);
    ushort* O2  = (ushort*)(smem + 71680);
    ushort* Pp  = (ushort*)(smem + 71680);   // disjoint in time from O2

    int tid = threadIdx.x;
    int lane = tid & 63; int w = tid >> 6;             // w = head
    int lr = lane & 15, lg = lane >> 4;
    int nl = blockIdx.x; int n = n_base + nl;
    int b = n >> 6;
    const ushort* kcn = kc + (size_t)nl * 224 * 256;
    const ushort* vcn = vc + (size_t)nl * 256 * 224;
    ushort* Pw = Pp + w * 640;                          // [16 s][40 t]

    bf16x8 qf[7];
    #pragma unroll
    for (int mt = 0; mt < 7; ++mt)
        qf[mt] = *(const bf16x8*)(qcp + ((((size_t)(b * 8 + w)) * 112 + mt * 16 + lr) * 32 + lg * 8));

    bf16x8 ones;
    #pragma unroll
    for (int j = 0; j < 8; ++j) ones[j] = (short)0x3F80;

    f32x4 o_acc[7][2], l_acc[7];
    #pragma unroll
    for (int mt = 0; mt < 7; ++mt) {
        f32x4 z = {0.f,0.f,0.f,0.f};
        o_acc[mt][0] = z; o_acc[mt][1] = z; l_acc[mt] = z;
    }

    const ushort* kbase = kcn + (size_t)lr * 256 + w * 32 + lg * 8;
    const ushort* vbase = vcn + ((size_t)(w * 32 + lr)) * 224 + lg * 8;

    bf16x8 ck0, ck1, cv0, cv1;
    ck0 = *(const bf16x8*)(kbase);
    ck1 = *(const bf16x8*)(kbase + 16 * 256);
    cv0 = *(const bf16x8*)(vbase);
    cv1 = *(const bf16x8*)(vbase + 16 * 224);

    for (int ch = 0; ch < 7; ++ch) {
        int t0 = ch * 32;
        bf16x8 nk0, nk1, nv0, nv1;
        if (ch < 6) {   // T14: next chunk's fragments issued before compute
            int t0n = t0 + 32;
            nk0 = *(const bf16x8*)(kbase + (size_t)t0n * 256);
            nk1 = *(const bf16x8*)(kbase + (size_t)(t0n + 16) * 256);
            nv0 = *(const bf16x8*)(vbase + t0n);
            nv1 = *(const bf16x8*)(vbase + 16 * 224 + t0n);
            if (t0n == 192) {   // last chunk: zero V elements with t >= 196
                #pragma unroll
                for (int j = 0; j < 8; ++j) {
                    bool inv = (lg * 8 + j) >= 4;
                    nv0[j] = inv ? (short)0 : nv0[j];
                    nv1[j] = inv ? (short)0 : nv1[j];
                }
            }
        }
        bool mask0 = (t0 + lr)      >= 196;
        bool mask1 = (t0 + 16 + lr) >= 196;
        #pragma unroll
        for (int mt = 0; mt < 7; ++mt) {
            f32x4 z = {0.f,0.f,0.f,0.f};
            f32x4 s0 = MFMA(qf[mt], ck0, z);
            f32x4 s1 = MFMA(qf[mt], ck1, z);
            #pragma unroll
            for (int r = 0; r < 4; ++r) {
                float p0 = mask0 ? 0.f : __expf(s0[r]);
                float p1 = mask1 ? 0.f : __expf(s1[r]);
                Pw[(lg * 4 + r) * 40 + lr]      = f2bf(p0);
                Pw[(lg * 4 + r) * 40 + 16 + lr] = f2bf(p1);
            }
            bf16x8 pf = *(const bf16x8*)(&Pw[lr * 40 + lg * 8]);
            o_acc[mt][0] = MFMA(pf, cv0, o_acc[mt][0]);
            o_acc[mt][1] = MFMA(pf, cv1, o_acc[mt][1]);
            l_acc[mt]    = MFMA(pf, ones, l_acc[mt]);
        }
        ck0 = nk0; ck1 = nk1; cv0 = nv0; cv1 = nv1;
    }

    __syncthreads();   // all waves done with Pp before O2 overlay
    // normalized O -> OL[112][264] (wave-private columns)
    #pragma unroll
    for (int mt = 0; mt < 7; ++mt) {
        #pragma unroll
        for (int r = 0; r < 4; ++r) {
            float inv = 1.f / l_acc[mt][r];
            int srow = mt * 16 + lg * 4 + r;
            OL[srow * 264 + w * 32 + lr]      = f2bf(o_acc[mt][0][r] * inv);
            OL[srow * 264 + w * 32 + 16 + lr] = f2bf(o_acc[mt][1][r] * inv);
        }
    }
    __syncthreads();

    // o2 = OL @ wo_c^T + bo_c
    {
        f32x4 a2[7][2];
        #pragma unroll
        for (int mt = 0; mt < 7; ++mt)
            #pragma unroll
            for (int nt = 0; nt < 2; ++nt) { f32x4 z = {0.f,0.f,0.f,0.f}; a2[mt][nt] = z; }
        for (int ks = 0; ks < 8; ++ks) {
            int c0 = ks * 32;
            bf16x8 bw[2];
            #pragma unroll
            for (int nt = 0; nt < 2; ++nt)
                bw[nt] = *(const bf16x8*)(Wall + (size_t)(1792 + w * 32 + nt * 16 + lr) * 256 + c0 + lg * 8);
            #pragma unroll
            for (int mt = 0; mt < 7; ++mt) {
                bf16x8 af = *(const bf16x8*)(&OL[(mt * 16 + lr) * 264 + c0 + lg * 8]);
                a2[mt][0] = MFMA(af, bw[0], a2[mt][0]);
                a2[mt][1] = MFMA(af, bw[1], a2[mt][1]);
            }
        }
        #pragma unroll
        for (int mt = 0; mt < 7; ++mt)
            #pragma unroll
            for (int nt = 0; nt < 2; ++nt) {
                float bias = Ball[1792 + w * 32 + nt * 16 + lr];
                #pragma unroll
                for (int r = 0; r < 4; ++r) {
                    int srow = mt * 16 + lg * 4 + r;
                    O2[srow * 264 + w * 32 + nt * 16 + lr] = f2bf(a2[mt][nt][r] + bias);
                }
            }
    }
    __syncthreads();

    // h1 = relu(O2 @ w1^T + b1) -> OL
    {
        f32x4 a2[7][2];
        #pragma unroll
        for (int mt = 0; mt < 7; ++mt)
            #pragma unroll
            for (int nt = 0; nt < 2; ++nt) { f32x4 z = {0.f,0.f,0.f,0.f}; a2[mt][nt] = z; }
        for (int ks = 0; ks < 8; ++ks) {
            int c0 = ks * 32;
            bf16x8 bw[2];
            #pragma unroll
            for (int nt = 0; nt < 2; ++nt)
                bw[nt] = *(const bf16x8*)(Wall + (size_t)(2048 + w * 32 + nt * 16 + lr) * 256 + c0 + lg * 8);
            #pragma unroll
            for (int mt = 0; mt < 7; ++mt) {
                bf16x8 af = *(const bf16x8*)(&O2[(mt * 16 + lr) * 264 + c0 + lg * 8]);
                a2[mt][0] = MFMA(af, bw[0], a2[mt][0]);
                a2[mt][1] = MFMA(af, bw[1], a2[mt][1]);
            }
        }
        __syncthreads();   // all OL reads (oproj phase) complete before overwrite
        #pragma unroll
        for (int mt = 0; mt < 7; ++mt)
            #pragma unroll
            for (int nt = 0; nt < 2; ++nt) {
                float bias = Ball[2048 + w * 32 + nt * 16 + lr];
                #pragma unroll
                for (int r = 0; r < 4; ++r) {
                    int srow = mt * 16 + lg * 4 + r;
                    float v = a2[mt][nt][r] + bias;
                    v = v > 0.f ? v : 0.f;
                    OL[srow * 264 + w * 32 + nt * 16 + lr] = f2bf(v);
                }
            }
    }
    __syncthreads();

    // hbar[c] = mean_s<100 h1[s][c];  score partials from O2
    if (tid < 256) {
        float s = 0.f;
        for (int srow = 0; srow < 100; ++srow) s += bf2f(OL[srow * 264 + tid]);
        hbar[tid] = s * 0.01f;
    }
    if (tid < 100) {
        float s = 0.f;
        for (int c2 = 0; c2 < 256; ++c2)
            s += bf2f(O2[tid * 264 + c2]) * bf2f(Wall[(size_t)2336 * 256 + c2]);
        s += Ball[2336];
        scb[tid] = 1.f / (1.f + __expf(-s));
    }
    __syncthreads();
    if (tid < 32) {
        float s = 0.f;
        for (int c2 = 0; c2 < 256; ++c2)
            s += hbar[c2] * bf2f(Wall[(size_t)(2304 + tid) * 256 + c2]);
        s += Ball[2304 + tid];
        outp[(size_t)n * 32 + tid] = s;
    }
    if (tid == 64) {
        float s = 0.f;
        for (int i2 = 0; i2 < 100; ++i2) s += scb[i2];
        outp[16384 + n] = s * 0.01f;
    }
}

// ---------------------------------------------------------------------------
extern "C" void kernel_launch(void* const* d_in, const int* in_sizes, int n_in,
                              void* d_out, int out_size, void* d_ws, size_t ws_size,
                              hipStream_t stream)
{
    const float* features = (const float*)d_in[0];
    const float* qfeat    = (const float*)d_in[1];
    char* ws = (char*)d_ws;

    ushort* wbf  = (ushort*)ws;                    //  2337*256 bf16
    float*  bias = (float*)(ws + 1196544);         //  2337 f32
    ushort* qkv  = (ushort*)(ws + 1206016);        //  800*768
    ushort* sav  = (ushort*)(ws + 2434816);        //  800*256
    ushort* osb  = (ushort*)(ws + 2844416);        //  800*256
    ushort* qcp  = (ushort*)(ws + 3254016);        //  8*8*112*32
    ushort* kvb  = (ushort*)(ws + 3712768);

    prep_kernel<<<dim3(512), dim3(256), 0, stream>>>(
        (const float*)d_in[2], (const float*)d_in[3], (const float*)d_in[4],
        (const float*)d_in[8], (const float*)d_in[10], (const float*)d_in[11],
        (const float*)d_in[12], (const float*)d_in[16], (const float*)d_in[18],
        (const float*)d_in[20], (const float*)d_in[22],
        (const float*)d_in[5], (const float*)d_in[6], (const float*)d_in[7],
        (const float*)d_in[9], (const float*)d_in[13], (const float*)d_in[14],
        (const float*)d_in[15], (const float*)d_in[17], (const float*)d_in[19],
        (const float*)d_in[21], (const float*)d_in[23],
        wbf, bias, qcp);

    // self-attention chain
    gemm_rows<1, 100, 0><<<dim3(13, 6), dim3(256), 0, stream>>>(
        qfeat, wbf, bias, qkv, 800, 0, 0, 768);
    self_attn<<<dim3(64), dim3(128), 0, stream>>>(qkv, sav);
    gemm_rows<0, 1, 0><<<dim3(13, 2), dim3(256), 0, stream>>>(
        sav, wbf, bias, osb, 800, 768, 768, 256);
    gemm_rows<0, 1, 1><<<dim3(13, 2), dim3(256), 0, stream>>>(
        osb, wbf, bias, qcp, 800, 1024, 1024, 0);

    // cross-attention, pass-split on workspace budget
    const size_t per_n = 229376;               // bytes of kc+vc per proposal
    long avail = (long)ws_size - 3712768L;
    int Np = 512;
    if (avail < (long)(per_n * 512)) {
        Np = (int)(avail / (long)per_n);
        if (Np < 1) Np = 1;
    }
    ushort* kcb = kvb;                                   // [Np][224][256]
    ushort* vcb = kvb + (size_t)Np * 224 * 256;          // [Np][256][224]
    float* outp = (float*)d_out;
    for (int n0 = 0; n0 < 512; n0 += Np) {
        int cnt = (512 - n0 < Np) ? (512 - n0) : Np;
        kvproj<<<dim3(cnt, 2), dim3(512), 0, stream>>>(features, wbf, bias, kcb, vcb, n0);
        attn_fuse<<<dim3(cnt), dim3(512), 0, stream>>>(qcp, kcb, vcb, wbf, bias, outp, n0);
    }
}

// Round 12
// 210.352 us; speedup vs baseline: 1.7185x; 1.7185x over previous
//
#include <hip/hip_runtime.h>
#include <hip/hip_bf16.h>

// ---------------------------------------------------------------------------
// PolygonPredictionLayer: B=8,P=64,N=512,T=196(->224),S=100(->112),C=256,H=8,dh=32
// R12: kvproj v9 = R5's proven structure (1 block/proposal, featT[224][264],
//   persistent af[4][8] weights, ONE barrier) + pk2/uint2 staging (28 b64
//   writes vs 100 scalar u16) + pad-skip (13 tiles, t<196 write guards).
//   attn_fuse v2 (R11): barrier-free main loop, K/V frags direct from global,
//   K-pad masked pre-exp, V-pad zeroed in-register.
// ---------------------------------------------------------------------------

typedef __attribute__((ext_vector_type(8))) short bf16x8;
typedef __attribute__((ext_vector_type(4))) float f32x4;

__device__ __forceinline__ float bf2f(ushort u) {
    union { float f; uint u32; } v; v.u32 = ((uint)u) << 16; return v.f;
}
__device__ __forceinline__ ushort f2bf(float f) {
    union { float f; uint u; } v; v.f = f;
    uint r = v.u + 0x7FFF + ((v.u >> 16) & 1);
    return (ushort)(r >> 16);
}
__device__ __forceinline__ uint pk2(float a, float b) {
    __hip_bfloat162 h = __float22bfloat162_rn(make_float2(a, b));
    union { __hip_bfloat162 h2; uint u; } c; c.h2 = h; return c.u;
}
__device__ __forceinline__ f32x4 MFMA(bf16x8 a, bf16x8 b, f32x4 c) {
    return __builtin_amdgcn_mfma_f32_16x16x32_bf16(a, b, c, 0, 0, 0);
}

#define SCALE_DH 0.17677669529663687f  // 1/sqrt(32)

// ---------------- prep: weights+biases -> ws tables, qcp zero ---------------
#define TOTALW (2337 * 256)
#define QCPN   (8 * 8 * 112 * 32)
#define NBIAS  2337

__global__ void prep_kernel(const float* w0, const float* w1_, const float* w2_,
                            const float* w3, const float* w4, const float* w5,
                            const float* w6, const float* w7, const float* w8,
                            const float* w9, const float* w10,
                            const float* b0, const float* b1_, const float* b2_,
                            const float* b3, const float* b4, const float* b5,
                            const float* b6, const float* b7, const float* b8,
                            const float* b9, const float* b10,
                            ushort* wbf, float* bias, ushort* qcp)
{
    for (size_t i = blockIdx.x * blockDim.x + threadIdx.x;
         i < (size_t)TOTALW + QCPN + NBIAS; i += (size_t)gridDim.x * blockDim.x) {
        if (i < TOTALW) {
            int row = (int)(i >> 8), col = (int)(i & 255);
            const float* sp; int base;
            if      (row < 256)  { sp = w0;  base = 0; }
            else if (row < 512)  { sp = w1_; base = 256; }
            else if (row < 768)  { sp = w2_; base = 512; }
            else if (row < 1024) { sp = w3;  base = 768; }
            else if (row < 1280) { sp = w4;  base = 1024; }
            else if (row < 1536) { sp = w5;  base = 1280; }
            else if (row < 1792) { sp = w6;  base = 1536; }
            else if (row < 2048) { sp = w7;  base = 1792; }
            else if (row < 2304) { sp = w8;  base = 2048; }
            else if (row < 2336) { sp = w9;  base = 2304; }
            else                 { sp = w10; base = 2336; }
            wbf[i] = f2bf(sp[(size_t)(row - base) * 256 + col]);
        } else if (i < (size_t)TOTALW + QCPN) {
            qcp[i - TOTALW] = 0;
        } else {
            int idx = (int)(i - TOTALW - QCPN);
            const float* sp; int base;
            if      (idx < 256)  { sp = b0;  base = 0; }
            else if (idx < 512)  { sp = b1_; base = 256; }
            else if (idx < 768)  { sp = b2_; base = 512; }
            else if (idx < 1024) { sp = b3;  base = 768; }
            else if (idx < 1280) { sp = b4;  base = 1024; }
            else if (idx < 1536) { sp = b5;  base = 1280; }
            else if (idx < 1792) { sp = b6;  base = 1536; }
            else if (idx < 2048) { sp = b7;  base = 1792; }
            else if (idx < 2304) { sp = b8;  base = 2048; }
            else if (idx < 2336) { sp = b9;  base = 2304; }
            else                 { sp = b10; base = 2336; }
            bias[idx] = sp[idx - base];
        }
    }
}

// ---------------- generic small GEMM: out = A @ W^T + bias -----------------
template<int ASRC, int GS, int EPI>
__global__ __launch_bounds__(256)
void gemm_rows(const void* Aptr, const ushort* Wall, const float* Ball,
               ushort* Out, int M, int Wrow0, int Brow0, int ldo)
{
    __shared__ ushort As[64 * 40];
    __shared__ ushort Bs[128 * 40];
    int tid = threadIdx.x;
    int lane = tid & 63, w = tid >> 6;
    int lr = lane & 15, lg = lane >> 4;
    int r0 = blockIdx.x * 64;
    int j0 = blockIdx.y * 128;

    f32x4 acc[4][2];
    #pragma unroll
    for (int mt = 0; mt < 4; ++mt)
        #pragma unroll
        for (int nt = 0; nt < 2; ++nt) { f32x4 z = {0.f,0.f,0.f,0.f}; acc[mt][nt] = z; }

    for (int ks = 0; ks < 8; ++ks) {
        int c0 = ks * 32;
        {
            int i = tid >> 2, q = tid & 3;
            int r = r0 + i;
            if (ASRC == 0) {
                uint4 v = make_uint4(0u,0u,0u,0u);
                if (r < M) v = *(const uint4*)((const ushort*)Aptr + (size_t)r * 256 + c0 + q * 8);
                *(uint4*)(&As[i * 40 + q * 8]) = v;
            } else {
                uint u[4] = {0u,0u,0u,0u};
                if (r < M) {
                    int g = r / GS, o = r - g * GS;
                    const float* src = (const float*)Aptr + (size_t)g * 256 * GS + o;
                    #pragma unroll
                    for (int k2 = 0; k2 < 4; ++k2) {
                        ushort a0 = f2bf(src[(size_t)(c0 + q * 8 + 2 * k2)     * GS]);
                        ushort a1 = f2bf(src[(size_t)(c0 + q * 8 + 2 * k2 + 1) * GS]);
                        u[k2] = (uint)a0 | ((uint)a1 << 16);
                    }
                }
                *(uint4*)(&As[i * 40 + q * 8]) = make_uint4(u[0], u[1], u[2], u[3]);
            }
        }
        {
            int jj = tid >> 1, half = tid & 1;
            const ushort* src = Wall + (size_t)(Wrow0 + j0 + jj) * 256 + c0 + half * 16;
            ushort* dst = &Bs[jj * 40 + half * 16];
            *(uint4*)(dst)     = *(const uint4*)(src);
            *(uint4*)(dst + 8) = *(const uint4*)(src + 8);
        }
        __syncthreads();
        bf16x8 bfr[2];
        #pragma unroll
        for (int nt = 0; nt < 2; ++nt)
            bfr[nt] = *(const bf16x8*)(&Bs[(w * 32 + nt * 16 + lr) * 40 + lg * 8]);
        #pragma unroll
        for (int mt = 0; mt < 4; ++mt) {
            bf16x8 afr = *(const bf16x8*)(&As[(mt * 16 + lr) * 40 + lg * 8]);
            acc[mt][0] = MFMA(afr, bfr[0], acc[mt][0]);
            acc[mt][1] = MFMA(afr, bfr[1], acc[mt][1]);
        }
        __syncthreads();
    }
    #pragma unroll
    for (int mt = 0; mt < 4; ++mt) {
        #pragma unroll
        for (int nt = 0; nt < 2; ++nt) {
            int jc = j0 + w * 32 + nt * 16 + lr;
            float bias = Ball[Brow0 + jc];
            #pragma unroll
            for (int rg = 0; rg < 4; ++rg) {
                int r = r0 + mt * 16 + lg * 4 + rg;
                if (r >= M) continue;
                float vv = acc[mt][nt][rg] + bias;
                if (EPI == 0) {
                    Out[(size_t)r * ldo + jc] = f2bf(vv);
                } else {
                    int b = r / 100, s = r - b * 100;
                    int h = jc >> 5, d = jc & 31;
                    Out[(((size_t)(b * 8 + h)) * 112 + s) * 32 + d] = f2bf(vv * SCALE_DH);
                }
            }
        }
    }
}

// ---------------- self-attention (tiny, VALU) ------------------------------
__global__ __launch_bounds__(128)
void self_attn(const ushort* qkv, ushort* sav)
{
    __shared__ float kls[100][33];
    __shared__ float vls[100][33];
    __shared__ float sls[100][101];
    int bh = blockIdx.x; int b = bh >> 3, h = bh & 7;
    int tid = threadIdx.x;
    for (int idx = tid; idx < 100 * 32; idx += 128) {
        int t = idx >> 5, d = idx & 31;
        kls[t][d] = bf2f(qkv[((size_t)(b * 100 + t)) * 768 + 256 + h * 32 + d]);
        vls[t][d] = bf2f(qkv[((size_t)(b * 100 + t)) * 768 + 512 + h * 32 + d]);
    }
    __syncthreads();
    if (tid < 100) {
        int s = tid;
        float q[32];
        #pragma unroll
        for (int d = 0; d < 32; ++d)
            q[d] = bf2f(qkv[((size_t)(b * 100 + s)) * 768 + h * 32 + d]) * SCALE_DH;
        float mx = -1e30f;
        for (int t = 0; t < 100; ++t) {
            float sc = 0.f;
            #pragma unroll
            for (int d = 0; d < 32; ++d) sc += q[d] * kls[t][d];
            sls[s][t] = sc; mx = fmaxf(mx, sc);
        }
        float sum = 0.f;
        for (int t = 0; t < 100; ++t) {
            float p = __expf(sls[s][t] - mx);
            sls[s][t] = p; sum += p;
        }
        float inv = 1.f / sum;
        float acc2[32];
        #pragma unroll
        for (int d = 0; d < 32; ++d) acc2[d] = 0.f;
        for (int t = 0; t < 100; ++t) {
            float pv = sls[s][t];
            #pragma unroll
            for (int d = 0; d < 32; ++d) acc2[d] += pv * vls[t][d];
        }
        #pragma unroll
        for (int d = 0; d < 32; ++d)
            sav[((size_t)(b * 100 + s)) * 256 + h * 32 + d] = f2bf(acc2[d] * inv);
    }
}

// ---------------- kvproj v9: kc[n][224][256] t-major, vc[n][256][224] ------
// One block per proposal (grid cnt), block 512 (8 waves), LDS featT[224][264]
// bf16 (118272 B -> 1 block/CU). Weights persistent af[4][8] (R5's proven
// shape, VGPR 88). Staging: item = 4 c-rows x 4 t -> 4 float4 loads, 8 pk2,
// 4 uint2 LDS writes. Pad: zero rows 196..207; 13 compute tiles; t<196 guards.
__global__ __launch_bounds__(512, 2)
void kvproj(const float* features, const ushort* Wall, const float* Ball,
            ushort* kc, ushort* vc, int n_base)
{
    __shared__ ushort featT[224 * 264];
    int tid = threadIdx.x;
    int lane = tid & 63, w = tid >> 6;
    int lr = lane & 15, lg = lane >> 4;
    int nl = blockIdx.x;
    int n  = n_base + nl;
    const float* fb = features + (size_t)n * 256 * 196;

    // persistent weight A-frags: m 0,1 = K couts (w*32, +16); m 2,3 = V couts
    bf16x8 af[4][8];
    #pragma unroll
    for (int m = 0; m < 4; ++m) {
        int row = ((m < 2) ? 1280 : 1536) + w * 32 + (m & 1) * 16 + lr;
        #pragma unroll
        for (int ks = 0; ks < 8; ++ks)
            af[m][ks] = *(const bf16x8*)(Wall + (size_t)row * 256 + ks * 32 + lg * 8);
    }
    float biask0 = Ball[1280 + w * 32 + lr];
    float biask1 = Ball[1296 + w * 32 + lr];
    float biasv0 = Ball[1536 + w * 32 + lr];
    float biasv1 = Ball[1552 + w * 32 + lr];

    // stage featT[t][c] = fb[c][t]; items = (cg 0..63 = 4 c-rows) x (tq 0..48)
    #pragma unroll
    for (int it = 0; it < 7; ++it) {
        int idx = tid + it * 512;
        if (idx < 3136) {
            int cg = idx / 49, tq = idx - cg * 49;
            const float* p = fb + (size_t)(cg * 4) * 196 + tq * 4;
            float4 v0 = *(const float4*)(p);
            float4 v1 = *(const float4*)(p + 196);
            float4 v2 = *(const float4*)(p + 392);
            float4 v3 = *(const float4*)(p + 588);
            #pragma unroll
            for (int j = 0; j < 4; ++j) {
                float e0 = (j == 0) ? v0.x : (j == 1) ? v0.y : (j == 2) ? v0.z : v0.w;
                float e1 = (j == 0) ? v1.x : (j == 1) ? v1.y : (j == 2) ? v1.z : v1.w;
                float e2 = (j == 0) ? v2.x : (j == 1) ? v2.y : (j == 2) ? v2.z : v2.w;
                float e3 = (j == 0) ? v3.x : (j == 1) ? v3.y : (j == 2) ? v3.z : v3.w;
                uint2 pr;
                pr.x = pk2(e0, e1);
                pr.y = pk2(e2, e3);
                *(uint2*)(&featT[(tq * 4 + j) * 264 + cg * 4]) = pr;
            }
        }
    }
    // zero pad rows 196..207 (read by tile 12)
    for (int idx = tid; idx < 12 * 264; idx += 512)
        featT[196 * 264 + idx] = 0;
    __syncthreads();   // the only barrier

    for (int tt = 0; tt < 13; ++tt) {
        bf16x8 a8[8];
        #pragma unroll
        for (int ks = 0; ks < 8; ++ks)
            a8[ks] = *(const bf16x8*)(&featT[(tt * 16 + lr) * 264 + ks * 32 + lg * 8]);
        f32x4 acc[4];
        #pragma unroll
        for (int m = 0; m < 4; ++m) { f32x4 z = {0.f,0.f,0.f,0.f}; acc[m] = z; }
        #pragma unroll
        for (int ks = 0; ks < 8; ++ks)
            #pragma unroll
            for (int m = 0; m < 4; ++m)
                acc[m] = MFMA(a8[ks], af[m][ks], acc[m]);

        // D[row = t = tb+rg][col = cout-local = lr]
        int tb = tt * 16 + lg * 4;
        #pragma unroll
        for (int rg = 0; rg < 4; ++rg) {
            int t = tb + rg;
            if (t < 196) {
                kc[((size_t)nl * 224 + t) * 256 + w * 32 + lr]      = f2bf(acc[0][rg] + biask0);
                kc[((size_t)nl * 224 + t) * 256 + w * 32 + 16 + lr] = f2bf(acc[1][rg] + biask1);
            }
        }
        if (tb < 196) {   // tb%4==0 -> tb<=192 -> t range tb..tb+3 <= 195
            size_t vb0 = ((size_t)nl * 256 + w * 32 + lr) * 224 + tb;
            size_t vb1 = ((size_t)nl * 256 + w * 32 + 16 + lr) * 224 + tb;
            uint a01 = pk2(acc[2][0] + biasv0, acc[2][1] + biasv0);
            uint a23 = pk2(acc[2][2] + biasv0, acc[2][3] + biasv0);
            uint b01 = pk2(acc[3][0] + biasv1, acc[3][1] + biasv1);
            uint b23 = pk2(acc[3][2] + biasv1, acc[3][3] + biasv1);
            *(uint*)(vc + vb0)     = a01;
            *(uint*)(vc + vb0 + 2) = a23;
            *(uint*)(vc + vb1)     = b01;
            *(uint*)(vc + vb1 + 2) = b23;
        }
    }
}

// ---------------- attn_fuse v2: barrier-free main loop ---------------------
// block 512 (8 waves, wave = head). K/V fragments loaded DIRECTLY from global
// (kc t-major, vc c-major are frag-contiguous); double-buffered in registers.
// Pad handling: K garbage masked pre-exp; V pad elements zeroed in-register
// on the last chunk's prefetch (P=0 x V=0, never 0 x garbage).
// LDS: Pp[8][16][40] @71680 (main loop). Epilogue overlay: OL[112][264] @0 |
// hbar @59392 | scb @60416 | O2[112][264] @71680.
__global__ __launch_bounds__(512, 2)
void attn_fuse(const ushort* qcp, const ushort* kc, const ushort* vc,
               const ushort* Wall, const float* Ball, float* outp, int n_base)
{
    __shared__ char smem[130816];
    ushort* OL  = (ushort*)smem;
    float* hbar = (float*)(smem + 59392);
    float* scb  = (float*)(smem + 60416);
    ushort* O2  = (ushort*)(smem + 71680);
    ushort* Pp  = (ushort*)(smem + 71680);   // disjoint in time from O2

    int tid = threadIdx.x;
    int lane = tid & 63; int w = tid >> 6;             // w = head
    int lr = lane & 15, lg = lane >> 4;
    int nl = blockIdx.x; int n = n_base + nl;
    int b = n >> 6;
    const ushort* kcn = kc + (size_t)nl * 224 * 256;
    const ushort* vcn = vc + (size_t)nl * 256 * 224;
    ushort* Pw = Pp + w * 640;                          // [16 s][40 t]

    bf16x8 qf[7];
    #pragma unroll
    for (int mt = 0; mt < 7; ++mt)
        qf[mt] = *(const bf16x8*)(qcp + ((((size_t)(b * 8 + w)) * 112 + mt * 16 + lr) * 32 + lg * 8));

    bf16x8 ones;
    #pragma unroll
    for (int j = 0; j < 8; ++j) ones[j] = (short)0x3F80;

    f32x4 o_acc[7][2], l_acc[7];
    #pragma unroll
    for (int mt = 0; mt < 7; ++mt) {
        f32x4 z = {0.f,0.f,0.f,0.f};
        o_acc[mt][0] = z; o_acc[mt][1] = z; l_acc[mt] = z;
    }

    const ushort* kbase = kcn + (size_t)lr * 256 + w * 32 + lg * 8;
    const ushort* vbase = vcn + ((size_t)(w * 32 + lr)) * 224 + lg * 8;

    bf16x8 ck0, ck1, cv0, cv1;
    ck0 = *(const bf16x8*)(kbase);
    ck1 = *(const bf16x8*)(kbase + 16 * 256);
    cv0 = *(const bf16x8*)(vbase);
    cv1 = *(const bf16x8*)(vbase + 16 * 224);

    for (int ch = 0; ch < 7; ++ch) {
        int t0 = ch * 32;
        bf16x8 nk0, nk1, nv0, nv1;
        if (ch < 6) {   // T14: next chunk's fragments issued before compute
            int t0n = t0 + 32;
            nk0 = *(const bf16x8*)(kbase + (size_t)t0n * 256);
            nk1 = *(const bf16x8*)(kbase + (size_t)(t0n + 16) * 256);
            nv0 = *(const bf16x8*)(vbase + t0n);
            nv1 = *(const bf16x8*)(vbase + 16 * 224 + t0n);
            if (t0n == 192) {   // last chunk: zero V elements with t >= 196
                #pragma unroll
                for (int j = 0; j < 8; ++j) {
                    bool inv = (lg * 8 + j) >= 4;
                    nv0[j] = inv ? (short)0 : nv0[j];
                    nv1[j] = inv ? (short)0 : nv1[j];
                }
            }
        }
        bool mask0 = (t0 + lr)      >= 196;
        bool mask1 = (t0 + 16 + lr) >= 196;
        #pragma unroll
        for (int mt = 0; mt < 7; ++mt) {
            f32x4 z = {0.f,0.f,0.f,0.f};
            f32x4 s0 = MFMA(qf[mt], ck0, z);
            f32x4 s1 = MFMA(qf[mt], ck1, z);
            #pragma unroll
            for (int r = 0; r < 4; ++r) {
                float p0 = mask0 ? 0.f : __expf(s0[r]);
                float p1 = mask1 ? 0.f : __expf(s1[r]);
                Pw[(lg * 4 + r) * 40 + lr]      = f2bf(p0);
                Pw[(lg * 4 + r) * 40 + 16 + lr] = f2bf(p1);
            }
            bf16x8 pf = *(const bf16x8*)(&Pw[lr * 40 + lg * 8]);
            o_acc[mt][0] = MFMA(pf, cv0, o_acc[mt][0]);
            o_acc[mt][1] = MFMA(pf, cv1, o_acc[mt][1]);
            l_acc[mt]    = MFMA(pf, ones, l_acc[mt]);
        }
        ck0 = nk0; ck1 = nk1; cv0 = nv0; cv1 = nv1;
    }

    __syncthreads();   // all waves done with Pp before O2 overlay
    // normalized O -> OL[112][264] (wave-private columns)
    #pragma unroll
    for (int mt = 0; mt < 7; ++mt) {
        #pragma unroll
        for (int r = 0; r < 4; ++r) {
            float inv = 1.f / l_acc[mt][r];
            int srow = mt * 16 + lg * 4 + r;
            OL[srow * 264 + w * 32 + lr]      = f2bf(o_acc[mt][0][r] * inv);
            OL[srow * 264 + w * 32 + 16 + lr] = f2bf(o_acc[mt][1][r] * inv);
        }
    }
    __syncthreads();

    // o2 = OL @ wo_c^T + bo_c
    {
        f32x4 a2[7][2];
        #pragma unroll
        for (int mt = 0; mt < 7; ++mt)
            #pragma unroll
            for (int nt = 0; nt < 2; ++nt) { f32x4 z = {0.f,0.f,0.f,0.f}; a2[mt][nt] = z; }
        for (int ks = 0; ks < 8; ++ks) {
            int c0 = ks * 32;
            bf16x8 bw[2];
            #pragma unroll
            for (int nt = 0; nt < 2; ++nt)
                bw[nt] = *(const bf16x8*)(Wall + (size_t)(1792 + w * 32 + nt * 16 + lr) * 256 + c0 + lg * 8);
            #pragma unroll
            for (int mt = 0; mt < 7; ++mt) {
                bf16x8 af = *(const bf16x8*)(&OL[(mt * 16 + lr) * 264 + c0 + lg * 8]);
                a2[mt][0] = MFMA(af, bw[0], a2[mt][0]);
                a2[mt][1] = MFMA(af, bw[1], a2[mt][1]);
            }
        }
        #pragma unroll
        for (int mt = 0; mt < 7; ++mt)
            #pragma unroll
            for (int nt = 0; nt < 2; ++nt) {
                float bias = Ball[1792 + w * 32 + nt * 16 + lr];
                #pragma unroll
                for (int r = 0; r < 4; ++r) {
                    int srow = mt * 16 + lg * 4 + r;
                    O2[srow * 264 + w * 32 + nt * 16 + lr] = f2bf(a2[mt][nt][r] + bias);
                }
            }
    }
    __syncthreads();

    // h1 = relu(O2 @ w1^T + b1) -> OL
    {
        f32x4 a2[7][2];
        #pragma unroll
        for (int mt = 0; mt < 7; ++mt)
            #pragma unroll
            for (int nt = 0; nt < 2; ++nt) { f32x4 z = {0.f,0.f,0.f,0.f}; a2[mt][nt] = z; }
        for (int ks = 0; ks < 8; ++ks) {
            int c0 = ks * 32;
            bf16x8 bw[2];
            #pragma unroll
            for (int nt = 0; nt < 2; ++nt)
                bw[nt] = *(const bf16x8*)(Wall + (size_t)(2048 + w * 32 + nt * 16 + lr) * 256 + c0 + lg * 8);
            #pragma unroll
            for (int mt = 0; mt < 7; ++mt) {
                bf16x8 af = *(const bf16x8*)(&O2[(mt * 16 + lr) * 264 + c0 + lg * 8]);
                a2[mt][0] = MFMA(af, bw[0], a2[mt][0]);
                a2[mt][1] = MFMA(af, bw[1], a2[mt][1]);
            }
        }
        __syncthreads();   // all OL reads (oproj phase) complete before overwrite
        #pragma unroll
        for (int mt = 0; mt < 7; ++mt)
            #pragma unroll
            for (int nt = 0; nt < 2; ++nt) {
                float bias = Ball[2048 + w * 32 + nt * 16 + lr];
                #pragma unroll
                for (int r = 0; r < 4; ++r) {
                    int srow = mt * 16 + lg * 4 + r;
                    float v = a2[mt][nt][r] + bias;
                    v = v > 0.f ? v : 0.f;
                    OL[srow * 264 + w * 32 + nt * 16 + lr] = f2bf(v);
                }
            }
    }
    __syncthreads();

    // hbar[c] = mean_s<100 h1[s][c];  score partials from O2
    if (tid < 256) {
        float s = 0.f;
        for (int srow = 0; srow < 100; ++srow) s += bf2f(OL[srow * 264 + tid]);
        hbar[tid] = s * 0.01f;
    }
    if (tid < 100) {
        float s = 0.f;
        for (int c2 = 0; c2 < 256; ++c2)
            s += bf2f(O2[tid * 264 + c2]) * bf2f(Wall[(size_t)2336 * 256 + c2]);
        s += Ball[2336];
        scb[tid] = 1.f / (1.f + __expf(-s));
    }
    __syncthreads();
    if (tid < 32) {
        float s = 0.f;
        for (int c2 = 0; c2 < 256; ++c2)
            s += hbar[c2] * bf2f(Wall[(size_t)(2304 + tid) * 256 + c2]);
        s += Ball[2304 + tid];
        outp[(size_t)n * 32 + tid] = s;
    }
    if (tid == 64) {
        float s = 0.f;
        for (int i2 = 0; i2 < 100; ++i2) s += scb[i2];
        outp[16384 + n] = s * 0.01f;
    }
}

// ---------------------------------------------------------------------------
extern "C" void kernel_launch(void* const* d_in, const int* in_sizes, int n_in,
                              void* d_out, int out_size, void* d_ws, size_t ws_size,
                              hipStream_t stream)
{
    const float* features = (const float*)d_in[0];
    const float* qfeat    = (const float*)d_in[1];
    char* ws = (char*)d_ws;

    ushort* wbf  = (ushort*)ws;                    //  2337*256 bf16
    float*  bias = (float*)(ws + 1196544);         //  2337 f32
    ushort* qkv  = (ushort*)(ws + 1206016);        //  800*768
    ushort* sav  = (ushort*)(ws + 2434816);        //  800*256
    ushort* osb  = (ushort*)(ws + 2844416);        //  800*256
    ushort* qcp  = (ushort*)(ws + 3254016);        //  8*8*112*32
    ushort* kvb  = (ushort*)(ws + 3712768);

    prep_kernel<<<dim3(512), dim3(256), 0, stream>>>(
        (const float*)d_in[2], (const float*)d_in[3], (const float*)d_in[4],
        (const float*)d_in[8], (const float*)d_in[10], (const float*)d_in[11],
        (const float*)d_in[12], (const float*)d_in[16], (const float*)d_in[18],
        (const float*)d_in[20], (const float*)d_in[22],
        (const float*)d_in[5], (const float*)d_in[6], (const float*)d_in[7],
        (const float*)d_in[9], (const float*)d_in[13], (const float*)d_in[14],
        (const float*)d_in[15], (const float*)d_in[17], (const float*)d_in[19],
        (const float*)d_in[21], (const float*)d_in[23],
        wbf, bias, qcp);

    // self-attention chain
    gemm_rows<1, 100, 0><<<dim3(13, 6), dim3(256), 0, stream>>>(
        qfeat, wbf, bias, qkv, 800, 0, 0, 768);
    self_attn<<<dim3(64), dim3(128), 0, stream>>>(qkv, sav);
    gemm_rows<0, 1, 0><<<dim3(13, 2), dim3(256), 0, stream>>>(
        sav, wbf, bias, osb, 800, 768, 768, 256);
    gemm_rows<0, 1, 1><<<dim3(13, 2), dim3(256), 0, stream>>>(
        osb, wbf, bias, qcp, 800, 1024, 1024, 0);

    // cross-attention, pass-split on workspace budget
    const size_t per_n = 229376;               // bytes of kc+vc per proposal
    long avail = (long)ws_size - 3712768L;
    int Np = 512;
    if (avail < (long)(per_n * 512)) {
        Np = (int)(avail / (long)per_n);
        if (Np < 1) Np = 1;
    }
    ushort* kcb = kvb;                                   // [Np][224][256]
    ushort* vcb = kvb + (size_t)Np * 224 * 256;          // [Np][256][224]
    float* outp = (float*)d_out;
    for (int n0 = 0; n0 < 512; n0 += Np) {
        int cnt = (512 - n0 < Np) ? (512 - n0) : Np;
        kvproj<<<dim3(cnt), dim3(512), 0, stream>>>(features, wbf, bias, kcb, vcb, n0);
        attn_fuse<<<dim3(cnt), dim3(512), 0, stream>>>(qcp, kcb, vcb, wbf, bias, outp, n0);
    }
}

// Round 13
// 206.562 us; speedup vs baseline: 1.7500x; 1.0183x over previous
//
#include <hip/hip_runtime.h>
#include <hip/hip_bf16.h>

// ---------------------------------------------------------------------------
// PolygonPredictionLayer: B=8,P=64,N=512,T=196(->224),S=100(->112),C=256,H=8,dh=32
// R13: attn_fuse v4 -- swapped QK^T (MFMA(K,Q) = S^T) puts P lane-local in the
//   exact PV A-fragment layout (k-slot permutation pi(8lg+j) = 4lg+j / 16+4lg+
//   (j-4), matched on the V B-side by two uint2 loads). P never touches LDS:
//   main loop is 5 MFMA + 8 exp + 4 pk2 per mt, zero ds ops. kvproj v9 and
//   the rest unchanged from R12 (210us best).
// ---------------------------------------------------------------------------

typedef __attribute__((ext_vector_type(8))) short bf16x8;
typedef __attribute__((ext_vector_type(4))) float f32x4;

__device__ __forceinline__ float bf2f(ushort u) {
    union { float f; uint u32; } v; v.u32 = ((uint)u) << 16; return v.f;
}
__device__ __forceinline__ ushort f2bf(float f) {
    union { float f; uint u; } v; v.f = f;
    uint r = v.u + 0x7FFF + ((v.u >> 16) & 1);
    return (ushort)(r >> 16);
}
__device__ __forceinline__ uint pk2(float a, float b) {
    __hip_bfloat162 h = __float22bfloat162_rn(make_float2(a, b));
    union { __hip_bfloat162 h2; uint u; } c; c.h2 = h; return c.u;
}
__device__ __forceinline__ f32x4 MFMA(bf16x8 a, bf16x8 b, f32x4 c) {
    return __builtin_amdgcn_mfma_f32_16x16x32_bf16(a, b, c, 0, 0, 0);
}

#define SCALE_DH 0.17677669529663687f  // 1/sqrt(32)

// ---------------- prep: weights+biases -> ws tables, qcp zero ---------------
#define TOTALW (2337 * 256)
#define QCPN   (8 * 8 * 112 * 32)
#define NBIAS  2337

__global__ void prep_kernel(const float* w0, const float* w1_, const float* w2_,
                            const float* w3, const float* w4, const float* w5,
                            const float* w6, const float* w7, const float* w8,
                            const float* w9, const float* w10,
                            const float* b0, const float* b1_, const float* b2_,
                            const float* b3, const float* b4, const float* b5,
                            const float* b6, const float* b7, const float* b8,
                            const float* b9, const float* b10,
                            ushort* wbf, float* bias, ushort* qcp)
{
    for (size_t i = blockIdx.x * blockDim.x + threadIdx.x;
         i < (size_t)TOTALW + QCPN + NBIAS; i += (size_t)gridDim.x * blockDim.x) {
        if (i < TOTALW) {
            int row = (int)(i >> 8), col = (int)(i & 255);
            const float* sp; int base;
            if      (row < 256)  { sp = w0;  base = 0; }
            else if (row < 512)  { sp = w1_; base = 256; }
            else if (row < 768)  { sp = w2_; base = 512; }
            else if (row < 1024) { sp = w3;  base = 768; }
            else if (row < 1280) { sp = w4;  base = 1024; }
            else if (row < 1536) { sp = w5;  base = 1280; }
            else if (row < 1792) { sp = w6;  base = 1536; }
            else if (row < 2048) { sp = w7;  base = 1792; }
            else if (row < 2304) { sp = w8;  base = 2048; }
            else if (row < 2336) { sp = w9;  base = 2304; }
            else                 { sp = w10; base = 2336; }
            wbf[i] = f2bf(sp[(size_t)(row - base) * 256 + col]);
        } else if (i < (size_t)TOTALW + QCPN) {
            qcp[i - TOTALW] = 0;
        } else {
            int idx = (int)(i - TOTALW - QCPN);
            const float* sp; int base;
            if      (idx < 256)  { sp = b0;  base = 0; }
            else if (idx < 512)  { sp = b1_; base = 256; }
            else if (idx < 768)  { sp = b2_; base = 512; }
            else if (idx < 1024) { sp = b3;  base = 768; }
            else if (idx < 1280) { sp = b4;  base = 1024; }
            else if (idx < 1536) { sp = b5;  base = 1280; }
            else if (idx < 1792) { sp = b6;  base = 1536; }
            else if (idx < 2048) { sp = b7;  base = 1792; }
            else if (idx < 2304) { sp = b8;  base = 2048; }
            else if (idx < 2336) { sp = b9;  base = 2304; }
            else                 { sp = b10; base = 2336; }
            bias[idx] = sp[idx - base];
        }
    }
}

// ---------------- generic small GEMM: out = A @ W^T + bias -----------------
template<int ASRC, int GS, int EPI>
__global__ __launch_bounds__(256)
void gemm_rows(const void* Aptr, const ushort* Wall, const float* Ball,
               ushort* Out, int M, int Wrow0, int Brow0, int ldo)
{
    __shared__ ushort As[64 * 40];
    __shared__ ushort Bs[128 * 40];
    int tid = threadIdx.x;
    int lane = tid & 63, w = tid >> 6;
    int lr = lane & 15, lg = lane >> 4;
    int r0 = blockIdx.x * 64;
    int j0 = blockIdx.y * 128;

    f32x4 acc[4][2];
    #pragma unroll
    for (int mt = 0; mt < 4; ++mt)
        #pragma unroll
        for (int nt = 0; nt < 2; ++nt) { f32x4 z = {0.f,0.f,0.f,0.f}; acc[mt][nt] = z; }

    for (int ks = 0; ks < 8; ++ks) {
        int c0 = ks * 32;
        {
            int i = tid >> 2, q = tid & 3;
            int r = r0 + i;
            if (ASRC == 0) {
                uint4 v = make_uint4(0u,0u,0u,0u);
                if (r < M) v = *(const uint4*)((const ushort*)Aptr + (size_t)r * 256 + c0 + q * 8);
                *(uint4*)(&As[i * 40 + q * 8]) = v;
            } else {
                uint u[4] = {0u,0u,0u,0u};
                if (r < M) {
                    int g = r / GS, o = r - g * GS;
                    const float* src = (const float*)Aptr + (size_t)g * 256 * GS + o;
                    #pragma unroll
                    for (int k2 = 0; k2 < 4; ++k2) {
                        ushort a0 = f2bf(src[(size_t)(c0 + q * 8 + 2 * k2)     * GS]);
                        ushort a1 = f2bf(src[(size_t)(c0 + q * 8 + 2 * k2 + 1) * GS]);
                        u[k2] = (uint)a0 | ((uint)a1 << 16);
                    }
                }
                *(uint4*)(&As[i * 40 + q * 8]) = make_uint4(u[0], u[1], u[2], u[3]);
            }
        }
        {
            int jj = tid >> 1, half = tid & 1;
            const ushort* src = Wall + (size_t)(Wrow0 + j0 + jj) * 256 + c0 + half * 16;
            ushort* dst = &Bs[jj * 40 + half * 16];
            *(uint4*)(dst)     = *(const uint4*)(src);
            *(uint4*)(dst + 8) = *(const uint4*)(src + 8);
        }
        __syncthreads();
        bf16x8 bfr[2];
        #pragma unroll
        for (int nt = 0; nt < 2; ++nt)
            bfr[nt] = *(const bf16x8*)(&Bs[(w * 32 + nt * 16 + lr) * 40 + lg * 8]);
        #pragma unroll
        for (int mt = 0; mt < 4; ++mt) {
            bf16x8 afr = *(const bf16x8*)(&As[(mt * 16 + lr) * 40 + lg * 8]);
            acc[mt][0] = MFMA(afr, bfr[0], acc[mt][0]);
            acc[mt][1] = MFMA(afr, bfr[1], acc[mt][1]);
        }
        __syncthreads();
    }
    #pragma unroll
    for (int mt = 0; mt < 4; ++mt) {
        #pragma unroll
        for (int nt = 0; nt < 2; ++nt) {
            int jc = j0 + w * 32 + nt * 16 + lr;
            float bias = Ball[Brow0 + jc];
            #pragma unroll
            for (int rg = 0; rg < 4; ++rg) {
                int r = r0 + mt * 16 + lg * 4 + rg;
                if (r >= M) continue;
                float vv = acc[mt][nt][rg] + bias;
                if (EPI == 0) {
                    Out[(size_t)r * ldo + jc] = f2bf(vv);
                } else {
                    int b = r / 100, s = r - b * 100;
                    int h = jc >> 5, d = jc & 31;
                    Out[(((size_t)(b * 8 + h)) * 112 + s) * 32 + d] = f2bf(vv * SCALE_DH);
                }
            }
        }
    }
}

// ---------------- self-attention (tiny, VALU) ------------------------------
__global__ __launch_bounds__(128)
void self_attn(const ushort* qkv, ushort* sav)
{
    __shared__ float kls[100][33];
    __shared__ float vls[100][33];
    __shared__ float sls[100][101];
    int bh = blockIdx.x; int b = bh >> 3, h = bh & 7;
    int tid = threadIdx.x;
    for (int idx = tid; idx < 100 * 32; idx += 128) {
        int t = idx >> 5, d = idx & 31;
        kls[t][d] = bf2f(qkv[((size_t)(b * 100 + t)) * 768 + 256 + h * 32 + d]);
        vls[t][d] = bf2f(qkv[((size_t)(b * 100 + t)) * 768 + 512 + h * 32 + d]);
    }
    __syncthreads();
    if (tid < 100) {
        int s = tid;
        float q[32];
        #pragma unroll
        for (int d = 0; d < 32; ++d)
            q[d] = bf2f(qkv[((size_t)(b * 100 + s)) * 768 + h * 32 + d]) * SCALE_DH;
        float mx = -1e30f;
        for (int t = 0; t < 100; ++t) {
            float sc = 0.f;
            #pragma unroll
            for (int d = 0; d < 32; ++d) sc += q[d] * kls[t][d];
            sls[s][t] = sc; mx = fmaxf(mx, sc);
        }
        float sum = 0.f;
        for (int t = 0; t < 100; ++t) {
            float p = __expf(sls[s][t] - mx);
            sls[s][t] = p; sum += p;
        }
        float inv = 1.f / sum;
        float acc2[32];
        #pragma unroll
        for (int d = 0; d < 32; ++d) acc2[d] = 0.f;
        for (int t = 0; t < 100; ++t) {
            float pv = sls[s][t];
            #pragma unroll
            for (int d = 0; d < 32; ++d) acc2[d] += pv * vls[t][d];
        }
        #pragma unroll
        for (int d = 0; d < 32; ++d)
            sav[((size_t)(b * 100 + s)) * 256 + h * 32 + d] = f2bf(acc2[d] * inv);
    }
}

// ---------------- kvproj v9: kc[n][224][256] t-major, vc[n][256][224] ------
// One block per proposal, block 512 (8 waves), LDS featT[224][264] bf16.
// Weights persistent af[4][8]. pk2/uint2 staging. Pad skipped (13 tiles).
__global__ __launch_bounds__(512, 2)
void kvproj(const float* features, const ushort* Wall, const float* Ball,
            ushort* kc, ushort* vc, int n_base)
{
    __shared__ ushort featT[224 * 264];
    int tid = threadIdx.x;
    int lane = tid & 63, w = tid >> 6;
    int lr = lane & 15, lg = lane >> 4;
    int nl = blockIdx.x;
    int n  = n_base + nl;
    const float* fb = features + (size_t)n * 256 * 196;

    bf16x8 af[4][8];
    #pragma unroll
    for (int m = 0; m < 4; ++m) {
        int row = ((m < 2) ? 1280 : 1536) + w * 32 + (m & 1) * 16 + lr;
        #pragma unroll
        for (int ks = 0; ks < 8; ++ks)
            af[m][ks] = *(const bf16x8*)(Wall + (size_t)row * 256 + ks * 32 + lg * 8);
    }
    float biask0 = Ball[1280 + w * 32 + lr];
    float biask1 = Ball[1296 + w * 32 + lr];
    float biasv0 = Ball[1536 + w * 32 + lr];
    float biasv1 = Ball[1552 + w * 32 + lr];

    #pragma unroll
    for (int it = 0; it < 7; ++it) {
        int idx = tid + it * 512;
        if (idx < 3136) {
            int cg = idx / 49, tq = idx - cg * 49;
            const float* p = fb + (size_t)(cg * 4) * 196 + tq * 4;
            float4 v0 = *(const float4*)(p);
            float4 v1 = *(const float4*)(p + 196);
            float4 v2 = *(const float4*)(p + 392);
            float4 v3 = *(const float4*)(p + 588);
            #pragma unroll
            for (int j = 0; j < 4; ++j) {
                float e0 = (j == 0) ? v0.x : (j == 1) ? v0.y : (j == 2) ? v0.z : v0.w;
                float e1 = (j == 0) ? v1.x : (j == 1) ? v1.y : (j == 2) ? v1.z : v1.w;
                float e2 = (j == 0) ? v2.x : (j == 1) ? v2.y : (j == 2) ? v2.z : v2.w;
                float e3 = (j == 0) ? v3.x : (j == 1) ? v3.y : (j == 2) ? v3.z : v3.w;
                uint2 pr;
                pr.x = pk2(e0, e1);
                pr.y = pk2(e2, e3);
                *(uint2*)(&featT[(tq * 4 + j) * 264 + cg * 4]) = pr;
            }
        }
    }
    for (int idx = tid; idx < 12 * 264; idx += 512)
        featT[196 * 264 + idx] = 0;
    __syncthreads();   // the only barrier

    for (int tt = 0; tt < 13; ++tt) {
        bf16x8 a8[8];
        #pragma unroll
        for (int ks = 0; ks < 8; ++ks)
            a8[ks] = *(const bf16x8*)(&featT[(tt * 16 + lr) * 264 + ks * 32 + lg * 8]);
        f32x4 acc[4];
        #pragma unroll
        for (int m = 0; m < 4; ++m) { f32x4 z = {0.f,0.f,0.f,0.f}; acc[m] = z; }
        #pragma unroll
        for (int ks = 0; ks < 8; ++ks)
            #pragma unroll
            for (int m = 0; m < 4; ++m)
                acc[m] = MFMA(a8[ks], af[m][ks], acc[m]);

        int tb = tt * 16 + lg * 4;
        #pragma unroll
        for (int rg = 0; rg < 4; ++rg) {
            int t = tb + rg;
            if (t < 196) {
                kc[((size_t)nl * 224 + t) * 256 + w * 32 + lr]      = f2bf(acc[0][rg] + biask0);
                kc[((size_t)nl * 224 + t) * 256 + w * 32 + 16 + lr] = f2bf(acc[1][rg] + biask1);
            }
        }
        if (tb < 196) {
            size_t vb0 = ((size_t)nl * 256 + w * 32 + lr) * 224 + tb;
            size_t vb1 = ((size_t)nl * 256 + w * 32 + 16 + lr) * 224 + tb;
            uint a01 = pk2(acc[2][0] + biasv0, acc[2][1] + biasv0);
            uint a23 = pk2(acc[2][2] + biasv0, acc[2][3] + biasv0);
            uint b01 = pk2(acc[3][0] + biasv1, acc[3][1] + biasv1);
            uint b23 = pk2(acc[3][2] + biasv1, acc[3][3] + biasv1);
            *(uint*)(vc + vb0)     = a01;
            *(uint*)(vc + vb0 + 2) = a23;
            *(uint*)(vc + vb1)     = b01;
            *(uint*)(vc + vb1 + 2) = b23;
        }
    }
}

// ---------------- attn_fuse v4: swapped QK^T, zero-LDS main loop -----------
// block 512 (8 waves, wave = head). S^T = MFMA(K,Q): lane holds P[s=mt*16+lr]
// [t = t0 + pi(k)] with pi(8lg+j) = 4lg+j (j<4) / 16+4lg+(j-4); V B-frags use
// the same pi via two uint2 loads per 16-col group. P stays in registers.
// LDS only for the epilogue: OL[112][264] @0 | hbar @59392 | scb @60416 |
// O2[112][264] @71680.
__global__ __launch_bounds__(512, 2)
void attn_fuse(const ushort* qcp, const ushort* kc, const ushort* vc,
               const ushort* Wall, const float* Ball, float* outp, int n_base)
{
    __shared__ char smem[130816];
    ushort* OL  = (ushort*)smem;
    float* hbar = (float*)(smem + 59392);
    float* scb  = (float*)(smem + 60416);
    ushort* O2  = (ushort*)(smem + 71680);

    int tid = threadIdx.x;
    int lane = tid & 63; int w = tid >> 6;             // w = head
    int lr = lane & 15, lg = lane >> 4;
    int nl = blockIdx.x; int n = n_base + nl;
    int b = n >> 6;
    const ushort* kcn = kc + (size_t)nl * 224 * 256;
    const ushort* vcn = vc + (size_t)nl * 256 * 224;

    bf16x8 qf[7];
    #pragma unroll
    for (int mt = 0; mt < 7; ++mt)
        qf[mt] = *(const bf16x8*)(qcp + ((((size_t)(b * 8 + w)) * 112 + mt * 16 + lr) * 32 + lg * 8));

    bf16x8 ones;
    #pragma unroll
    for (int j = 0; j < 8; ++j) ones[j] = (short)0x3F80;

    f32x4 o_acc[7][2], l_acc[7];
    #pragma unroll
    for (int mt = 0; mt < 7; ++mt) {
        f32x4 z = {0.f,0.f,0.f,0.f};
        o_acc[mt][0] = z; o_acc[mt][1] = z; l_acc[mt] = z;
    }

    // K fragment (A-operand): rows t = t0+lr (+16), k = d = w*32+lg*8+j
    const ushort* kbase = kcn + (size_t)lr * 256 + w * 32 + lg * 8;
    // V rows (c-major): vb0 = cout w*32+lr, vb1 = +16
    const ushort* vb0 = vcn + ((size_t)(w * 32 + lr)) * 224;
    const ushort* vb1 = vcn + ((size_t)(w * 32 + 16 + lr)) * 224;

    bf16x8 ck0, ck1;
    uint2 v0lo, v0hi, v1lo, v1hi;
    ck0 = *(const bf16x8*)(kbase);
    ck1 = *(const bf16x8*)(kbase + 16 * 256);
    v0lo = *(const uint2*)(vb0 + 4 * lg);
    v0hi = *(const uint2*)(vb0 + 16 + 4 * lg);
    v1lo = *(const uint2*)(vb1 + 4 * lg);
    v1hi = *(const uint2*)(vb1 + 16 + 4 * lg);

    for (int ch = 0; ch < 7; ++ch) {
        int t0 = ch * 32;
        bf16x8 nk0, nk1;
        uint2 n0lo, n0hi, n1lo, n1hi;
        if (ch < 6) {   // T14: next chunk's fragments issued before compute
            int t0n = t0 + 32;
            nk0 = *(const bf16x8*)(kbase + (size_t)t0n * 256);
            nk1 = *(const bf16x8*)(kbase + (size_t)(t0n + 16) * 256);
            n0lo = *(const uint2*)(vb0 + t0n + 4 * lg);
            n0hi = *(const uint2*)(vb0 + t0n + 16 + 4 * lg);
            n1lo = *(const uint2*)(vb1 + t0n + 4 * lg);
            n1hi = *(const uint2*)(vb1 + t0n + 16 + 4 * lg);
            if (t0n == 192) {   // zero V slots with t>=196 (0 x stale hazard)
                uint2 zz = make_uint2(0u, 0u);
                n0hi = zz; n1hi = zz;                 // t >= 208
                if (lg) { n0lo = zz; n1lo = zz; }     // t = 192+4lg.. >= 196
            }
        }
        // assemble V B-frags under pi
        union { uint4 q; bf16x8 v; } u0, u1;
        u0.q = make_uint4(v0lo.x, v0lo.y, v0hi.x, v0hi.y);
        u1.q = make_uint4(v1lo.x, v1lo.y, v1hi.x, v1hi.y);
        // masks for p slots (only chunk 6 has any)
        bool mA[4], mB[4];
        #pragma unroll
        for (int r = 0; r < 4; ++r) {
            mA[r] = (t0 + 4 * lg + r)      >= 196;
            mB[r] = (t0 + 16 + 4 * lg + r) >= 196;
        }
        #pragma unroll
        for (int mt = 0; mt < 7; ++mt) {
            f32x4 z = {0.f,0.f,0.f,0.f};
            f32x4 s0 = MFMA(ck0, qf[mt], z);   // swapped: rows t, cols s
            f32x4 s1 = MFMA(ck1, qf[mt], z);
            float p00 = mA[0] ? 0.f : __expf(s0[0]);
            float p01 = mA[1] ? 0.f : __expf(s0[1]);
            float p02 = mA[2] ? 0.f : __expf(s0[2]);
            float p03 = mA[3] ? 0.f : __expf(s0[3]);
            float p10 = mB[0] ? 0.f : __expf(s1[0]);
            float p11 = mB[1] ? 0.f : __expf(s1[1]);
            float p12 = mB[2] ? 0.f : __expf(s1[2]);
            float p13 = mB[3] ? 0.f : __expf(s1[3]);
            union { uint4 q; bf16x8 v; } pu;
            pu.q.x = pk2(p00, p01);
            pu.q.y = pk2(p02, p03);
            pu.q.z = pk2(p10, p11);
            pu.q.w = pk2(p12, p13);
            o_acc[mt][0] = MFMA(pu.v, u0.v, o_acc[mt][0]);
            o_acc[mt][1] = MFMA(pu.v, u1.v, o_acc[mt][1]);
            l_acc[mt]    = MFMA(pu.v, ones, l_acc[mt]);
        }
        ck0 = nk0; ck1 = nk1;
        v0lo = n0lo; v0hi = n0hi; v1lo = n1lo; v1hi = n1hi;
    }

    // normalized O -> OL[112][264] (wave-private columns)
    #pragma unroll
    for (int mt = 0; mt < 7; ++mt) {
        #pragma unroll
        for (int r = 0; r < 4; ++r) {
            float inv = 1.f / l_acc[mt][r];
            int srow = mt * 16 + lg * 4 + r;
            OL[srow * 264 + w * 32 + lr]      = f2bf(o_acc[mt][0][r] * inv);
            OL[srow * 264 + w * 32 + 16 + lr] = f2bf(o_acc[mt][1][r] * inv);
        }
    }
    __syncthreads();

    // o2 = OL @ wo_c^T + bo_c
    {
        f32x4 a2[7][2];
        #pragma unroll
        for (int mt = 0; mt < 7; ++mt)
            #pragma unroll
            for (int nt = 0; nt < 2; ++nt) { f32x4 z = {0.f,0.f,0.f,0.f}; a2[mt][nt] = z; }
        for (int ks = 0; ks < 8; ++ks) {
            int c0 = ks * 32;
            bf16x8 bw[2];
            #pragma unroll
            for (int nt = 0; nt < 2; ++nt)
                bw[nt] = *(const bf16x8*)(Wall + (size_t)(1792 + w * 32 + nt * 16 + lr) * 256 + c0 + lg * 8);
            #pragma unroll
            for (int mt = 0; mt < 7; ++mt) {
                bf16x8 af = *(const bf16x8*)(&OL[(mt * 16 + lr) * 264 + c0 + lg * 8]);
                a2[mt][0] = MFMA(af, bw[0], a2[mt][0]);
                a2[mt][1] = MFMA(af, bw[1], a2[mt][1]);
            }
        }
        #pragma unroll
        for (int mt = 0; mt < 7; ++mt)
            #pragma unroll
            for (int nt = 0; nt < 2; ++nt) {
                float bias = Ball[1792 + w * 32 + nt * 16 + lr];
                #pragma unroll
                for (int r = 0; r < 4; ++r) {
                    int srow = mt * 16 + lg * 4 + r;
                    O2[srow * 264 + w * 32 + nt * 16 + lr] = f2bf(a2[mt][nt][r] + bias);
                }
            }
    }
    __syncthreads();

    // h1 = relu(O2 @ w1^T + b1) -> OL
    {
        f32x4 a2[7][2];
        #pragma unroll
        for (int mt = 0; mt < 7; ++mt)
            #pragma unroll
            for (int nt = 0; nt < 2; ++nt) { f32x4 z = {0.f,0.f,0.f,0.f}; a2[mt][nt] = z; }
        for (int ks = 0; ks < 8; ++ks) {
            int c0 = ks * 32;
            bf16x8 bw[2];
            #pragma unroll
            for (int nt = 0; nt < 2; ++nt)
                bw[nt] = *(const bf16x8*)(Wall + (size_t)(2048 + w * 32 + nt * 16 + lr) * 256 + c0 + lg * 8);
            #pragma unroll
            for (int mt = 0; mt < 7; ++mt) {
                bf16x8 af = *(const bf16x8*)(&O2[(mt * 16 + lr) * 264 + c0 + lg * 8]);
                a2[mt][0] = MFMA(af, bw[0], a2[mt][0]);
                a2[mt][1] = MFMA(af, bw[1], a2[mt][1]);
            }
        }
        __syncthreads();   // all OL reads (oproj phase) complete before overwrite
        #pragma unroll
        for (int mt = 0; mt < 7; ++mt)
            #pragma unroll
            for (int nt = 0; nt < 2; ++nt) {
                float bias = Ball[2048 + w * 32 + nt * 16 + lr];
                #pragma unroll
                for (int r = 0; r < 4; ++r) {
                    int srow = mt * 16 + lg * 4 + r;
                    float v = a2[mt][nt][r] + bias;
                    v = v > 0.f ? v : 0.f;
                    OL[srow * 264 + w * 32 + nt * 16 + lr] = f2bf(v);
                }
            }
    }
    __syncthreads();

    // hbar[c] = mean_s<100 h1[s][c];  score partials from O2
    if (tid < 256) {
        float s = 0.f;
        for (int srow = 0; srow < 100; ++srow) s += bf2f(OL[srow * 264 + tid]);
        hbar[tid] = s * 0.01f;
    }
    if (tid < 100) {
        float s = 0.f;
        for (int c2 = 0; c2 < 256; ++c2)
            s += bf2f(O2[tid * 264 + c2]) * bf2f(Wall[(size_t)2336 * 256 + c2]);
        s += Ball[2336];
        scb[tid] = 1.f / (1.f + __expf(-s));
    }
    __syncthreads();
    if (tid < 32) {
        float s = 0.f;
        for (int c2 = 0; c2 < 256; ++c2)
            s += hbar[c2] * bf2f(Wall[(size_t)(2304 + tid) * 256 + c2]);
        s += Ball[2304 + tid];
        outp[(size_t)n * 32 + tid] = s;
    }
    if (tid == 64) {
        float s = 0.f;
        for (int i2 = 0; i2 < 100; ++i2) s += scb[i2];
        outp[16384 + n] = s * 0.01f;
    }
}

// ---------------------------------------------------------------------------
extern "C" void kernel_launch(void* const* d_in, const int* in_sizes, int n_in,
                              void* d_out, int out_size, void* d_ws, size_t ws_size,
                              hipStream_t stream)
{
    const float* features = (const float*)d_in[0];
    const float* qfeat    = (const float*)d_in[1];
    char* ws = (char*)d_ws;

    ushort* wbf  = (ushort*)ws;                    //  2337*256 bf16
    float*  bias = (float*)(ws + 1196544);         //  2337 f32
    ushort* qkv  = (ushort*)(ws + 1206016);        //  800*768
    ushort* sav  = (ushort*)(ws + 2434816);        //  800*256
    ushort* osb  = (ushort*)(ws + 2844416);        //  800*256
    ushort* qcp  = (ushort*)(ws + 3254016);        //  8*8*112*32
    ushort* kvb  = (ushort*)(ws + 3712768);

    prep_kernel<<<dim3(512), dim3(256), 0, stream>>>(
        (const float*)d_in[2], (const float*)d_in[3], (const float*)d_in[4],
        (const float*)d_in[8], (const float*)d_in[10], (const float*)d_in[11],
        (const float*)d_in[12], (const float*)d_in[16], (const float*)d_in[18],
        (const float*)d_in[20], (const float*)d_in[22],
        (const float*)d_in[5], (const float*)d_in[6], (const float*)d_in[7],
        (const float*)d_in[9], (const float*)d_in[13], (const float*)d_in[14],
        (const float*)d_in[15], (const float*)d_in[17], (const float*)d_in[19],
        (const float*)d_in[21], (const float*)d_in[23],
        wbf, bias, qcp);

    // self-attention chain
    gemm_rows<1, 100, 0><<<dim3(13, 6), dim3(256), 0, stream>>>(
        qfeat, wbf, bias, qkv, 800, 0, 0, 768);
    self_attn<<<dim3(64), dim3(128), 0, stream>>>(qkv, sav);
    gemm_rows<0, 1, 0><<<dim3(13, 2), dim3(256), 0, stream>>>(
        sav, wbf, bias, osb, 800, 768, 768, 256);
    gemm_rows<0, 1, 1><<<dim3(13, 2), dim3(256), 0, stream>>>(
        osb, wbf, bias, qcp, 800, 1024, 1024, 0);

    // cross-attention, pass-split on workspace budget
    const size_t per_n = 229376;               // bytes of kc+vc per proposal
    long avail = (long)ws_size - 3712768L;
    int Np = 512;
    if (avail < (long)(per_n * 512)) {
        Np = (int)(avail / (long)per_n);
        if (Np < 1) Np = 1;
    }
    ushort* kcb = kvb;                                   // [Np][224][256]
    ushort* vcb = kvb + (size_t)Np * 224 * 256;          // [Np][256][224]
    float* outp = (float*)d_out;
    for (int n0 = 0; n0 < 512; n0 += Np) {
        int cnt = (512 - n0 < Np) ? (512 - n0) : Np;
        kvproj<<<dim3(cnt), dim3(512), 0, stream>>>(features, wbf, bias, kcb, vcb, n0);
        attn_fuse<<<dim3(cnt), dim3(512), 0, stream>>>(qcp, kcb, vcb, wbf, bias, outp, n0);
    }
}